// Round 12
// baseline (267.307 us; speedup 1.0000x reference)
//
#include <hip/hip_runtime.h>
#include <hip/hip_bf16.h>
#include <stdint.h>

typedef __bf16 bf16x8 __attribute__((ext_vector_type(8)));
typedef float f32x4 __attribute__((ext_vector_type(4)));
typedef float f32x16 __attribute__((ext_vector_type(16)));
typedef uint32_t u32x4 __attribute__((ext_vector_type(4)));
typedef unsigned short ushort_t;
typedef unsigned short ushort8v __attribute__((ext_vector_type(8)));

#define MFMA16 __builtin_amdgcn_mfma_f32_16x16x32_bf16
#define MFMA32 __builtin_amdgcn_mfma_f32_32x32x16_bf16

static constexpr int Bc = 2, Sc = 2048, Ec = 2048, Hc = 16;

__device__ __forceinline__ void gload16(const void* g, void* l) {
  __builtin_amdgcn_global_load_lds(
      (const __attribute__((address_space(1))) void*)g,
      (__attribute__((address_space(3))) void*)l, 16, 0, 0);
}

__device__ __forceinline__ ushort_t f2bf(float f) {
  uint32_t u = __float_as_uint(f);
  uint32_t r = (u + 0x7fffu + ((u >> 16) & 1u)) >> 16;
  return (ushort_t)r;
}
__device__ __forceinline__ float bf2f(ushort_t u) {
  return __uint_as_float((uint32_t)u << 16);
}
__device__ __forceinline__ uint32_t cvtpk(float a, float b) {
  uint32_t d;
  asm("v_cvt_pk_bf16_f32 %0, %1, %2" : "=v"(d) : "v"(a), "v"(b));
  return d;
}
// exchange: a[lanes 32..63] <-> b[lanes 0..31]
__device__ __forceinline__ void plswap(uint32_t& a, uint32_t& b) {
  asm("v_permlane32_swap_b32 %0, %1" : "+v"(a), "+v"(b));
}

// ---------------- fused casts: all 5 weight/x tensors in one launch ----------------
__global__ void cast_all(const float* __restrict__ x, const float* __restrict__ Wq,
                         const float* __restrict__ Wkvu, const float* __restrict__ Wout,
                         const float* __restrict__ Wkvd,
                         ushort_t* __restrict__ xb, ushort_t* __restrict__ wq,
                         ushort_t* __restrict__ wkvu, ushort_t* __restrict__ wout,
                         ushort_t* __restrict__ wkvd) {
  int i = blockIdx.x * 256 + threadIdx.x;
  const float* src;
  ushort_t* dst;
  int j;
  if (i < 2097152) { src = x; dst = xb; j = i; }
  else if (i < 3145728) { src = Wq; dst = wq; j = i - 2097152; }
  else if (i < 3538944) { src = Wkvu; dst = wkvu; j = i - 3145728; }
  else if (i < 4587520) { src = Wout; dst = wout; j = i - 3538944; }
  else {
    j = i - 4587520;                      // wkvd with row pad 576->640
    int row = j >> 9, col4 = j & 511;
    ushort4 o;
    if (row < 576) {
      float4 v = ((const float4*)Wkvd)[row * 512 + col4];
      o.x = f2bf(v.x); o.y = f2bf(v.y); o.z = f2bf(v.z); o.w = f2bf(v.w);
    } else { o.x = 0; o.y = 0; o.z = 0; o.w = 0; }
    ((ushort4*)wkvd)[j] = o;
    return;
  }
  float4 v = ((const float4*)src)[j];
  ushort4 o;
  o.x = f2bf(v.x); o.y = f2bf(v.y); o.z = f2bf(v.z); o.w = f2bf(v.w);
  ((ushort4*)dst)[j] = o;
}

// ---------------- prep: mask rearrange (blocks 0..2047, lane-major) + rope fill ----------------
// mask unit (16B): u5 = ((qg*32 + kt)*4 + kblk*2 + rr)*64 + half*32 + (q&31)
//   element j = mask[q][kt*64 + kblk*32 + 4*half + (j&3) + 8*(2*rr+(j>>2))] / ln2
// kbuf layout: [bh][kt][kblk][ks][lane = halfq*32 + (s&31)][16B], qd = ks*16 + halfq*8 + e
__global__ void prep_kernel(const float* __restrict__ mask, ushort_t* __restrict__ m4,
                            const ushort_t* __restrict__ comp, char* __restrict__ kbuf) {
  const float INVLN2 = 1.4426950408889634f;
  int gb = blockIdx.x;
  if (gb < 2048) {
    int i = gb * 256 + threadIdx.x;   // 524288 units
    int rr = i & 1, half = (i >> 1) & 1, kblk = (i >> 2) & 1, kt = (i >> 3) & 31, q = i >> 8;
    const float* src = mask + (size_t)q * 2048 + kt * 64 + kblk * 32 + half * 4 + rr * 16;
    float4 a = *(const float4*)src;         // j=0..3
    float4 c = *(const float4*)(src + 8);   // j=4..7
    ushort8v o;
    o[0] = f2bf(a.x * INVLN2); o[1] = f2bf(a.y * INVLN2);
    o[2] = f2bf(a.z * INVLN2); o[3] = f2bf(a.w * INVLN2);
    o[4] = f2bf(c.x * INVLN2); o[5] = f2bf(c.y * INVLN2);
    o[6] = f2bf(c.z * INVLN2); o[7] = f2bf(c.w * INVLN2);
    size_t u5 = ((((size_t)(q >> 5) * 32 + kt) * 4 + kblk * 2 + rr) * 64) + half * 32 + (q & 31);
    ((ushort8v*)m4)[u5] = o;
  } else {
    int i = (gb - 2048) * 256 + threadIdx.x;  // B*S*8 = 32768 16-byte blocks
    int blk = i & 7;
    int m = i >> 3;
    int s = m & 2047, b = m >> 11;
    uint4 v = *(const uint4*)&comp[(size_t)m * 640 + 512 + blk * 8];
    int kt = s >> 6, kblk = (s & 63) >> 5;
    size_t base = (size_t)kt * 16384 + kblk * 8192 + (blk >> 1) * 1024 +
                  ((blk & 1) * 32 + (s & 31)) * 16;
#pragma unroll
    for (int h = 0; h < Hc; h++) {
      *(uint4*)(kbuf + (size_t)(b * Hc + h) * 524288 + base) = v;
    }
  }
}

// ---------------- GEMM: C[m][n] = sum_k A[m][k]*B[n][k], 128x128 tiles, BK=64 ----------------
// (round-9 verified structure: 32KB LDS, two K-slices per barrier period)
template<int MODE>
__global__ __launch_bounds__(256, 2)
void gemm_bt(const ushort_t* __restrict__ A, int lda,
             const ushort_t* __restrict__ Bm, int ldb,
             void* __restrict__ Cout, int ldc,
             int M, int N, int K,
             char* __restrict__ vtb, char* __restrict__ kbuf)
{
  __shared__ __align__(16) ushort_t sA[2][128 * 32];
  __shared__ __align__(16) ushort_t sB[2][128 * 32];
  int tid = threadIdx.x;
  int nTn = N >> 7;
  int bid = blockIdx.x;
  int chunk = gridDim.x >> 3;                       // grids are %8==0 -> bijective
  bid = (bid & 7) * chunk + (bid >> 3);             // XCD-chunked swizzle
  int tm = bid / nTn, tn = bid - tm * nTn;
  int wave = tid >> 6, lane = tid & 63;
  int wm = (wave >> 1) << 6, wn = (wave & 1) << 6;
  int l16 = lane & 15, g16 = lane >> 4;
  f32x4 acc[4][4] = {};
  int srow = tid >> 2, scol = (tid & 3) << 3;
  const ushort_t* Ag = A + (size_t)(tm * 128 + srow) * lda + scol;
  const ushort_t* Bg = Bm + (size_t)(tn * 128 + srow) * ldb + scol;
  ushort_t* sA0 = &sA[0][srow * 32 + scol];
  ushort_t* sA1 = &sA[1][srow * 32 + scol];
  ushort_t* sB0 = &sB[0][srow * 32 + scol];
  ushort_t* sB1 = &sB[1][srow * 32 + scol];
  for (int kt = 0; kt < K; kt += 64) {
    gload16(Ag, sA0);
    gload16(Ag + (size_t)64 * lda, sA0 + 64 * 32);
    gload16(Ag + 32, sA1);
    gload16(Ag + (size_t)64 * lda + 32, sA1 + 64 * 32);
    gload16(Bg, sB0);
    gload16(Bg + (size_t)64 * ldb, sB0 + 64 * 32);
    gload16(Bg + 32, sB1);
    gload16(Bg + (size_t)64 * ldb + 32, sB1 + 64 * 32);
    Ag += 64; Bg += 64;
    __syncthreads();
#pragma unroll
    for (int h2 = 0; h2 < 2; h2++) {
      bf16x8 af[4], bfr[4];
#pragma unroll
      for (int i = 0; i < 4; i++) af[i] = *(const bf16x8*)&sA[h2][(wm + i * 16 + l16) * 32 + g16 * 8];
#pragma unroll
      for (int i = 0; i < 4; i++) bfr[i] = *(const bf16x8*)&sB[h2][(wn + i * 16 + l16) * 32 + g16 * 8];
#pragma unroll
      for (int i = 0; i < 4; i++)
#pragma unroll
        for (int j = 0; j < 4; j++)
          acc[i][j] = MFMA16(af[i], bfr[j], acc[i][j], 0, 0, 0);
    }
    __syncthreads();
  }
  // epilogue: C/D layout col=lane&15, row=(lane>>4)*4+r
#pragma unroll
  for (int i = 0; i < 4; i++) {
#pragma unroll
    for (int j = 0; j < 4; j++) {
      int grow0 = tm * 128 + wm + i * 16 + g16 * 4;
      int gcol = tn * 128 + wn + j * 16 + l16;
      if constexpr (MODE == 0) {
#pragma unroll
        for (int r = 0; r < 4; r++)
          ((ushort_t*)Cout)[(size_t)(grow0 + r) * ldc + gcol] = f2bf(acc[i][j][r]);
      } else if constexpr (MODE == 2) {
#pragma unroll
        for (int r = 0; r < 4; r++)
          ((float*)Cout)[(size_t)(grow0 + r) * ldc + gcol] = acc[i][j][r];
      } else {
        int h = gcol / 192, jj = gcol - h * 192;
        int b = grow0 >> 11, s0 = grow0 & 2047;
        size_t bh = (size_t)(b * Hc + h);
        int kt = s0 >> 6, sl = s0 & 63;
        int kblk = sl >> 5, l32s = sl & 31;
        if (jj < 128) {
          // V frag layout: [bh][kt][kblk][k2][vb][lane = halfv*32 + (vd&31)][16B]
          int k2 = (sl >> 4) & 1, halfv = (sl >> 3) & 1, e0 = sl & 7;   // e0 in {0,4}
          ushort4 pk;
          pk.x = f2bf(acc[i][j][0]); pk.y = f2bf(acc[i][j][1]);
          pk.z = f2bf(acc[i][j][2]); pk.w = f2bf(acc[i][j][3]);
          *(ushort4*)(vtb + bh * 524288 + (size_t)kt * 16384 + kblk * 8192 + k2 * 4096 +
                      (jj >> 5) * 1024 + (halfv * 32 + (jj & 31)) * 16 + e0 * 2) = pk;
        } else {
          // K frag layout: [bh][kt][kblk][ks][lane = halfq*32 + l32][16B], qd 64..127
          int qd = jj - 64;
          int ks = qd >> 4, halfq = (qd >> 3) & 1, e = qd & 7;
          char* kp = kbuf + bh * 524288 + (size_t)kt * 16384 + kblk * 8192 + ks * 1024 +
                     (halfq * 32 + l32s) * 16 + e * 2;
#pragma unroll
          for (int r = 0; r < 4; r++)
            *(ushort_t*)(kp + r * 16) = f2bf(acc[i][j][r]);
        }
      }
    }
  }
}

// ---------------- flash attention: NO LDS, NO barriers — per-lane fragment loads from L2 ----------------
// 1 wave per block (64 thr), grid 2048 = 32 bh x 64 q-tiles of 32 rows; 8 waves/CU.
// K/V/mask pre-laid in MFMA fragment order -> every load is a coalesced 1KB per-wave read.
// Per-kblk phases; K ping-pong prefetch (issue after consumption); compiler auto-vmcnt.
__global__ __launch_bounds__(64, 2)
void attn_kernel(const ushort_t* __restrict__ qb, const char* __restrict__ kbuf,
                 const char* __restrict__ vtb, const ushort_t* __restrict__ m4,
                 ushort_t* __restrict__ attn_o)
{
  const float scale2 = 0.12752081738040466f;  // 128^-0.5 / ln2
  int bid = blockIdx.x;
  bid = (bid & 7) * 256 + (bid >> 3);        // XCD-chunked swizzle (2048 % 8 == 0)
  int qt = bid & 63, bh = bid >> 6;
  int b = bh >> 4, h = bh & 15;
  int l = threadIdx.x, l32 = l & 31, half = l >> 5;
  int qbase = qt * 32;

  // Q fragments (B-operand): col = q = l32, k = ks*16 + half*8 + e
  bf16x8 qf[8];
  {
    const ushort_t* qp = qb + (size_t)(b * Sc + qbase + l32) * 2048 + h * 128 + half * 8;
#pragma unroll
    for (int ks = 0; ks < 8; ks++) qf[ks] = *(const bf16x8*)(qp + ks * 16);
  }

  float mrun = -3.0e38f, lrun = 0.f;   // per-lane scalars for q = qbase + l32
  f32x16 acco[4] = {};                  // [vdblk]; rows = q reg-pattern, col = vd

  const char* kg = kbuf + (size_t)bh * 524288;
  const char* vg = vtb + (size_t)bh * 524288;
  const ushort8v* mbase = (const ushort8v*)m4 + (size_t)qt * 8192;
  int moff = half * 32 + l32;

  bf16x8 kfA[8], kfB[8];
  {
    const char* p = kg + l * 16;     // tile 0, kblk 0
#pragma unroll
    for (int ks = 0; ks < 8; ks++) kfA[ks] = *(const bf16x8*)(p + ks * 1024);
  }

  auto PHASE = [&](int kt, int kblk, bf16x8 (&kfc)[8], bf16x8 (&kfn)[8],
                   int ktn, int nkblk) {
    // V fragments for this (kt,kblk) — issue first, land during QK^T (coalesced 1KB each)
    bf16x8 vv[8];   // [k2*4 + vb]
    {
      const char* p = vg + (size_t)kt * 16384 + kblk * 8192 + l * 16;
#pragma unroll
      for (int i2 = 0; i2 < 8; i2++) vv[i2] = *(const bf16x8*)(p + i2 * 1024);
    }
    ushort8v mca = mbase[(kt * 4 + kblk * 2) * 64 + moff];
    ushort8v mcb = mbase[(kt * 4 + kblk * 2 + 1) * 64 + moff];

    // QK^T (swapped): sc rows = k (32), cols = q (32)
    f32x16 sc = {};
    __builtin_amdgcn_s_setprio(1);
#pragma unroll
    for (int ks = 0; ks < 8; ks++) sc = MFMA32(kfc[ks], qf[ks], sc, 0, 0, 0);
    __builtin_amdgcn_s_setprio(0);

    // prefetch next K fragments (kfc dead now); lands during softmax+PV
    {
      const char* p = kg + (size_t)ktn * 16384 + nkblk * 8192 + l * 16;
#pragma unroll
      for (int ks = 0; ks < 8; ks++) kfn[ks] = *(const bf16x8*)(p + ks * 1024);
    }

    // lane-local softmax: lane holds P[q=l32][k = (r&3)+8*(r>>2)+4*half + kblk*32]
#pragma unroll
    for (int r = 0; r < 16; r++)
      sc[r] = sc[r] * scale2 + bf2f((r < 8 ? mca : mcb)[r & 7]);
    float mx = sc[0];
#pragma unroll
    for (int r = 1; r < 16; r++) mx = fmaxf(mx, sc[r]);
    mx = fmaxf(mx, __shfl_xor(mx, 32));
    if (!__all(mx <= mrun + 11.0f)) {       // T13 defer-max (rare)
      float mnew = fmaxf(mrun, mx);
      float corr = __builtin_amdgcn_exp2f(mrun - mnew);
      lrun *= corr; mrun = mnew;
#pragma unroll
      for (int r = 0; r < 16; r++) {
        float cr = __shfl(corr, (r & 3) + 8 * (r >> 2) + 4 * half);
#pragma unroll
        for (int vb = 0; vb < 4; vb++) acco[vb][r] *= cr;
      }
    }
    float rs = 0.f;
    uint32_t W[8];
#pragma unroll
    for (int m = 0; m < 4; m++) {
      float p0 = __builtin_amdgcn_exp2f(sc[4 * m + 0] - mrun);
      float p1 = __builtin_amdgcn_exp2f(sc[4 * m + 1] - mrun);
      float p2 = __builtin_amdgcn_exp2f(sc[4 * m + 2] - mrun);
      float p3 = __builtin_amdgcn_exp2f(sc[4 * m + 3] - mrun);
      rs += (p0 + p1) + (p2 + p3);
      W[2 * m] = cvtpk(p0, p1);
      W[2 * m + 1] = cvtpk(p2, p3);
    }
    lrun += rs;   // lane-partial (this half's k); combined in epilogue

    // redistribute P to PV A-frag layout: frag[k2] k = k2*16 + half*8 + e
    bf16x8 pf[2];
#pragma unroll
    for (int k2 = 0; k2 < 2; k2++) {
      uint32_t a0 = W[4 * k2 + 0], a1 = W[4 * k2 + 1];
      uint32_t b0 = W[4 * k2 + 2], b1 = W[4 * k2 + 3];
      plswap(a0, b0);
      plswap(a1, b1);
      u32x4 t; t[0] = a0; t[1] = a1; t[2] = b0; t[3] = b1;
      pf[k2] = __builtin_bit_cast(bf16x8, t);
    }

    // PV: acco[vb] += P(32q x 32k) . V(32k x 128vd)  (vv waits auto-inserted)
    __builtin_amdgcn_s_setprio(1);
#pragma unroll
    for (int k2 = 0; k2 < 2; k2++)
#pragma unroll
      for (int vb = 0; vb < 4; vb++)
        acco[vb] = MFMA32(pf[k2], vv[k2 * 4 + vb], acco[vb], 0, 0, 0);
    __builtin_amdgcn_s_setprio(0);
  };

#pragma unroll 1
  for (int kt = 0; kt < 32; kt++) {
    PHASE(kt, 0, kfA, kfB, kt, 1);
    PHASE(kt, 1, kfB, kfA, (kt + 1) & 31, 0);
  }

  // epilogue: combine half-partial l, divide, store
  lrun += __shfl_xor(lrun, 32);
#pragma unroll
  for (int r = 0; r < 16; r++) {
    int rowq = (r & 3) + 8 * (r >> 2) + 4 * half;
    float lr = __shfl(lrun, rowq);
    float inv = 1.0f / lr;
    int qrow = qbase + rowq;
    ushort_t* op = attn_o + (size_t)(b * Sc + qrow) * 2048 + h * 128 + l32;
#pragma unroll
    for (int vb = 0; vb < 4; vb++)
      op[vb * 32] = f2bf(acco[vb][r] * inv);
  }
}

extern "C" void kernel_launch(void* const* d_in, const int* in_sizes, int n_in,
                              void* d_out, int out_size, void* d_ws, size_t ws_size,
                              hipStream_t stream) {
  const float* x    = (const float*)d_in[0];
  const float* mask = (const float*)d_in[1];
  const float* Wkvd = (const float*)d_in[2];
  const float* Wkvu = (const float*)d_in[3];
  const float* Wq   = (const float*)d_in[4];
  const float* Wout = (const float*)d_in[5];

  char* ws = (char*)d_ws;
  size_t off = 0;
  auto alloc = [&](size_t bytes) { char* p = ws + off; off += (bytes + 255) & ~(size_t)255; return p; };
  ushort_t* xb   = (ushort_t*)alloc((size_t)4096 * 2048 * 2);
  ushort_t* wkvd = (ushort_t*)alloc((size_t)640 * 2048 * 2);
  ushort_t* wq   = (ushort_t*)alloc((size_t)2048 * 2048 * 2);
  ushort_t* wkvu = (ushort_t*)alloc((size_t)3072 * 512 * 2);
  ushort_t* wout = (ushort_t*)alloc((size_t)2048 * 2048 * 2);
  ushort_t* comp = (ushort_t*)alloc((size_t)4096 * 640 * 2);
  ushort_t* qbuf = (ushort_t*)alloc((size_t)4096 * 2048 * 2);
  char*     kbuf = alloc((size_t)Bc * Hc * Sc * 256);
  char*     vtb  = alloc((size_t)Bc * Hc * 524288);
  ushort_t* attn_o = xb;   // xb dead after q-GEMM; reuse
  ushort_t* m4 = wq;       // wq dead after q-GEMM; reuse (8MB)

  // all casts in one launch
  cast_all<<<19200, 256, 0, stream>>>(x, Wq, Wkvu, Wout, Wkvd, xb, wq, wkvu, wout, wkvd);

  // compressed = x . W_kv_down^T  (N padded 576->640)
  gemm_bt<0><<<32 * 5, 256, 0, stream>>>(xb, 2048, wkvd, 2048, comp, 640, 4096, 640, 2048, nullptr, nullptr);
  // q = x . W_q^T
  gemm_bt<0><<<32 * 16, 256, 0, stream>>>(xb, 2048, wq, 2048, qbuf, 2048, 4096, 2048, 2048, nullptr, nullptr);
  // mask -> lane-major fragment order + rope broadcast into kbuf (frag layout)
  prep_kernel<<<2176, 256, 0, stream>>>(mask, m4, comp, kbuf);
  // kv_exp = kv_c . W_kv_up^T, scattered into vtb/kbuf fragment layouts
  gemm_bt<1><<<32 * 24, 256, 0, stream>>>(comp, 640, wkvu, 512, nullptr, 0, 4096, 3072, 512, vtb, kbuf);
  // flash attention (LDS-free, barrier-free; grid 2048 x 64 thr)
  attn_kernel<<<2048, 64, 0, stream>>>(qbuf, kbuf, vtb, m4, attn_o);
  // out = attn . W_out^T (fp32 store)
  gemm_bt<2><<<32 * 16, 256, 0, stream>>>(attn_o, 2048, wout, 2048, d_out, 2048, 4096, 2048, 2048, nullptr, nullptr);
}